// Round 1
// baseline (27245.773 us; speedup 1.0000x reference)
//
#include <hip/hip_runtime.h>
#include <hip/hip_bf16.h>

#define T_SEQ 1024
#define NB 128
#define HID 256
#define NTEAM 8
#define TEAM_BLK 32

typedef __attribute__((ext_vector_type(8))) short short8;
typedef __attribute__((ext_vector_type(4))) float f32x4;

__device__ __forceinline__ unsigned short f2bf(float f) {
  unsigned int u = __builtin_bit_cast(unsigned int, f);
  unsigned int r = (u + 0x7fffu + ((u >> 16) & 1u)) >> 16;
  return (unsigned short)r;
}

__device__ __forceinline__ float sigm(float x) { return 1.0f / (1.0f + expf(-x)); }

// LDS swizzle for weight tile wt[64][512] bf16 (row stride 1024B):
// spreads rows across bank groups so ds_read_b128 of 16 rows @ same k is ~2-way.
__device__ __forceinline__ int swz(int r, int k) {
  return (((r << 10) + (k << 1)) ^ ((r & 7) << 4)) >> 1;  // ushort index
}

// ---------------- conv encoder (fp32) ----------------

__global__ void conv1_kernel(const float* __restrict__ imu, const float* __restrict__ k1,
                             const float* __restrict__ g1, const float* __restrict__ b1,
                             const float* __restrict__ m1, const float* __restrict__ v1,
                             float* __restrict__ y1) {
  int idx = blockIdx.x * 256 + threadIdx.x;   // [B][T][64]
  int c = idx & 63;
  int t = (idx >> 6) & (T_SEQ - 1);
  int b = idx >> 16;
  float acc = 0.f;
#pragma unroll
  for (int dt = 0; dt < 3; ++dt) {
    int tt = t + dt - 1;
    if (tt >= 0 && tt < T_SEQ) {
      const float* ip = imu + ((size_t)b * T_SEQ + tt) * 6;
#pragma unroll
      for (int ci = 0; ci < 6; ++ci)
        acc += ip[ci] * k1[(dt * 6 + ci) * 64 + c];
    }
  }
  float sc = g1[c] * rsqrtf(v1[c] + 1e-3f);
  float y = (acc - m1[c]) * sc + b1[c];
  y1[idx] = y > 0.f ? y : 0.1f * y;
}

__global__ void conv2_kernel(const float* __restrict__ y1, const float* __restrict__ k2,
                             const float* __restrict__ g2, const float* __restrict__ b2,
                             const float* __restrict__ m2, const float* __restrict__ v2,
                             float* __restrict__ y2) {
  int b = blockIdx.x >> 7;            // 128 t-chunks of 8
  int t0 = (blockIdx.x & 127) * 8;
  int c = threadIdx.x & 127;
  int tb = t0 + ((threadIdx.x >> 7) << 2);
  float acc[4] = {0.f, 0.f, 0.f, 0.f};
  for (int dt = 0; dt < 3; ++dt) {
    for (int ci = 0; ci < 64; ++ci) {
      float w = k2[(dt * 64 + ci) * 128 + c];
#pragma unroll
      for (int u = 0; u < 4; ++u) {
        int tt = tb + u + dt - 1;
        float v = (tt >= 0 && tt < T_SEQ) ? y1[((size_t)b * T_SEQ + tt) * 64 + ci] : 0.f;
        acc[u] += v * w;
      }
    }
  }
  float sc = g2[c] * rsqrtf(v2[c] + 1e-3f);
  float sh = b2[c] - m2[c] * sc;
#pragma unroll
  for (int u = 0; u < 4; ++u) {
    float y = acc[u] * sc + sh;
    y2[((size_t)b * T_SEQ + (tb + u)) * 128 + c] = y > 0.f ? y : 0.1f * y;
  }
}

__global__ void conv3_kernel(const float* __restrict__ y2, const float* __restrict__ k3,
                             const float* __restrict__ g3, const float* __restrict__ b3,
                             const float* __restrict__ m3, const float* __restrict__ v3,
                             unsigned short* __restrict__ x) {  // x: [T][B][256] bf16
  int b = blockIdx.x >> 6;            // 64 t-chunks of 16
  int t0 = (blockIdx.x & 63) * 16;
  int c = threadIdx.x;                // 256
  float acc[16];
#pragma unroll
  for (int u = 0; u < 16; ++u) acc[u] = 0.f;
  for (int dt = 0; dt < 3; ++dt) {
    for (int ci = 0; ci < 128; ++ci) {
      float w = k3[(dt * 128 + ci) * 256 + c];
#pragma unroll
      for (int u = 0; u < 16; ++u) {
        int tt = t0 + u + dt - 1;
        float v = (tt >= 0 && tt < T_SEQ) ? y2[((size_t)b * T_SEQ + tt) * 128 + ci] : 0.f;
        acc[u] += v * w;
      }
    }
  }
  float sc = g3[c] * rsqrtf(v3[c] + 1e-3f);
  float sh = b3[c] - m3[c] * sc;
#pragma unroll
  for (int u = 0; u < 16; ++u) {
    float y = acc[u] * sc + sh;
    y = y > 0.f ? y : 0.1f * y;
    x[((size_t)(t0 + u) * NB + b) * HID + c] = f2bf(y);
  }
}

// ---------------- persistent pipelined LSTM ----------------

__device__ __forceinline__ void team_barrier(unsigned int* bar) {
  __threadfence();  // release our h writes (all lanes; also blocks load sinking)
  if (threadIdx.x == 0) {
    unsigned int g = __hip_atomic_load(bar + 32, __ATOMIC_RELAXED, __HIP_MEMORY_SCOPE_AGENT);
    unsigned int old = __hip_atomic_fetch_add(bar, 1u, __ATOMIC_ACQ_REL, __HIP_MEMORY_SCOPE_AGENT);
    if (old == TEAM_BLK - 1) {
      __hip_atomic_store(bar, 0u, __ATOMIC_RELAXED, __HIP_MEMORY_SCOPE_AGENT);
      __hip_atomic_fetch_add(bar + 32, 1u, __ATOMIC_RELEASE, __HIP_MEMORY_SCOPE_AGENT);
    } else {
      while (__hip_atomic_load(bar + 32, __ATOMIC_ACQUIRE, __HIP_MEMORY_SCOPE_AGENT) == g) {
        __builtin_amdgcn_s_sleep(1);
      }
    }
  }
  __threadfence();  // acquire; prevents hoisting next phase's loads above the spin
}

// Grid: 256 blocks x 64 threads. Team = 32 blocks = 16 L1-blocks + 16 L2-blocks,
// owns 16 batch rows. Block owns 16 h-columns (all 4 gates) of its layer.
// Phase k: L1 computes step t=k, L2 computes step t=k-1 (1 barrier/phase).
__global__ __launch_bounds__(64) void lstm_kernel(
    const unsigned short* __restrict__ x,   // [T][NB][256] bf16
    const float* __restrict__ W1, const float* __restrict__ U1, const float* __restrict__ bl1,
    const float* __restrict__ W2, const float* __restrict__ U2, const float* __restrict__ bl2,
    unsigned short* __restrict__ hbufs,     // [NTEAM][2 layers][2 bufs][16][256] bf16, zeroed
    unsigned int* __restrict__ bars,        // [NTEAM][64], zeroed
    float* __restrict__ out) {              // [128][256]
  __shared__ unsigned short wt[64 * 512];   // 64 KiB: [4 gates *16 cols][K=512] bf16, swizzled

  const int team = blockIdx.x >> 5;
  const int bid = blockIdx.x & 31;
  const bool is_l2 = bid >= 16;
  const int j0 = (bid & 15) << 4;
  const int lane = threadIdx.x;
  const int b0 = team << 4;

  const float* Wx = is_l2 ? W2 : W1;
  const float* Wh = is_l2 ? U2 : U1;
  const float* bl = is_l2 ? bl2 : bl1;

  // ---- stage weight slice into LDS (one-time). thread = wt row r = g*16+jj.
  {
    const int r = lane;
    const int col = ((r >> 4) << 8) + j0 + (r & 15);  // g*256 + j0 + jj
    for (int k0 = 0; k0 < 256; k0 += 8) {
      short8 sx, sh;
#pragma unroll
      for (int u = 0; u < 8; ++u) {
        sx[u] = (short)f2bf(Wx[(size_t)(k0 + u) * 1024 + col]);
        sh[u] = (short)f2bf(Wh[(size_t)(k0 + u) * 1024 + col]);
      }
      *(short8*)&wt[swz(r, k0)] = sx;
      *(short8*)&wt[swz(r, 256 + k0)] = sh;
    }
  }

  const int lo4 = lane & 15;          // A-row / B-col / D-col
  const int klo = (lane >> 4) << 3;   // k-base within 32-wide K step

  float bias[4];
#pragma unroll
  for (int g = 0; g < 4; ++g) bias[g] = bl[(g << 8) + j0 + lo4];

  unsigned short* h1buf = hbufs + (size_t)team * 16384;  // [2][16][256]
  unsigned short* h2buf = h1buf + 8192;
  unsigned int* bar = bars + team * 64;

  float cst[4] = {0.f, 0.f, 0.f, 0.f};
  float oacc[4] = {0.f, 0.f, 0.f, 0.f};

  for (int ph = 0; ph <= T_SEQ; ++ph) {
    const int t = is_l2 ? ph - 1 : ph;
    if (t >= 0 && t < T_SEQ) {
      const unsigned short* src0 = is_l2
          ? h1buf + (t & 1) * 4096 + lo4 * 256                        // h1[t]
          : x + ((size_t)t * NB + b0 + lo4) * HID;                    // x[t]
      const unsigned short* src1 = is_l2
          ? h2buf + ((t + 1) & 1) * 4096 + lo4 * 256                  // h2[t-1]
          : h1buf + ((t + 1) & 1) * 4096 + lo4 * 256;                 // h1[t-1]
      unsigned short* dst = (is_l2 ? h2buf : h1buf) + (t & 1) * 4096;

      f32x4 acc[4];
#pragma unroll
      for (int g = 0; g < 4; ++g) acc[g] = (f32x4){bias[g], bias[g], bias[g], bias[g]};

#pragma unroll
      for (int kk = 0; kk < 8; ++kk) {
        short8 a = *(const short8*)(src0 + kk * 32 + klo);
#pragma unroll
        for (int g = 0; g < 4; ++g) {
          short8 bf = *(const short8*)&wt[swz((g << 4) + lo4, (kk << 5) + klo)];
          acc[g] = __builtin_amdgcn_mfma_f32_16x16x32_bf16(a, bf, acc[g], 0, 0, 0);
        }
      }
#pragma unroll
      for (int kk = 0; kk < 8; ++kk) {
        short8 a = *(const short8*)(src1 + kk * 32 + klo);
#pragma unroll
        for (int g = 0; g < 4; ++g) {
          short8 bf = *(const short8*)&wt[swz((g << 4) + lo4, 256 + (kk << 5) + klo)];
          acc[g] = __builtin_amdgcn_mfma_f32_16x16x32_bf16(a, bf, acc[g], 0, 0, 0);
        }
      }

#pragma unroll
      for (int q = 0; q < 4; ++q) {
        float iv = acc[0][q], fv = acc[1][q], gv = acc[2][q], ov = acc[3][q];
        float cn = sigm(fv) * cst[q] + sigm(iv) * tanhf(gv);
        float hn = sigm(ov) * tanhf(cn);
        cst[q] = cn;
        int row = ((lane >> 4) << 2) + q;
        dst[row * 256 + j0 + lo4] = f2bf(hn);
        if (is_l2) oacc[q] += hn;
      }
    }
    team_barrier(bar);
  }

  if (is_l2) {
#pragma unroll
    for (int q = 0; q < 4; ++q) {
      int row = ((lane >> 4) << 2) + q;
      out[(size_t)(b0 + row) * HID + j0 + lo4] = oacc[q] * (1.0f / T_SEQ);
    }
  }
}

// ---------------- host ----------------

extern "C" void kernel_launch(void* const* d_in, const int* in_sizes, int n_in,
                              void* d_out, int out_size, void* d_ws, size_t ws_size,
                              hipStream_t stream) {
  const float* imu = (const float*)d_in[0];
  const float* k1 = (const float*)d_in[1];
  const float* g1 = (const float*)d_in[2];
  const float* b1 = (const float*)d_in[3];
  const float* m1 = (const float*)d_in[4];
  const float* v1 = (const float*)d_in[5];
  const float* k2 = (const float*)d_in[6];
  const float* g2 = (const float*)d_in[7];
  const float* b2 = (const float*)d_in[8];
  const float* m2 = (const float*)d_in[9];
  const float* v2 = (const float*)d_in[10];
  const float* k3 = (const float*)d_in[11];
  const float* g3 = (const float*)d_in[12];
  const float* b3 = (const float*)d_in[13];
  const float* m3 = (const float*)d_in[14];
  const float* v3 = (const float*)d_in[15];
  const float* W1 = (const float*)d_in[16];
  const float* U1 = (const float*)d_in[17];
  const float* bl1 = (const float*)d_in[18];
  const float* W2 = (const float*)d_in[19];
  const float* U2 = (const float*)d_in[20];
  const float* bl2 = (const float*)d_in[21];

  char* ws = (char*)d_ws;
  // layout: [0,64Mi) y2 fp32 [B][T][128]; [64Mi,96Mi) y1 fp32 [B][T][64];
  // [64Mi,128Mi) x bf16 [T][B][256] (overlaps y1 — y1 dead once conv2 done);
  // [128Mi,+256Ki) h buffers; then barrier words.
  float* y2 = (float*)ws;
  float* y1 = (float*)(ws + (64u << 20));
  unsigned short* xq = (unsigned short*)(ws + (64u << 20));
  unsigned short* hbufs = (unsigned short*)(ws + (128u << 20));
  unsigned int* bars = (unsigned int*)(ws + (128u << 20) + (256u << 10));

  hipMemsetAsync(ws + (128u << 20), 0, (256u << 10) + 2048, stream);

  conv1_kernel<<<32768, 256, 0, stream>>>(imu, k1, g1, b1, m1, v1, y1);
  conv2_kernel<<<16384, 256, 0, stream>>>(y1, k2, g2, b2, m2, v2, y2);
  conv3_kernel<<<8192, 256, 0, stream>>>(y2, k3, g3, b3, m3, v3, xq);
  lstm_kernel<<<256, 64, 0, stream>>>(xq, W1, U1, bl1, W2, U2, bl2, hbufs, bars,
                                      (float*)d_out);
}

// Round 2
// 7445.554 us; speedup vs baseline: 3.6593x; 3.6593x over previous
//
#include <hip/hip_runtime.h>
#include <hip/hip_bf16.h>

#define T_SEQ 1024
#define NB 128
#define HID 256
#define TEAM_BLK 32

typedef __attribute__((ext_vector_type(8))) short short8;
typedef __attribute__((ext_vector_type(4))) float f32x4;

__device__ __forceinline__ unsigned short f2bf(float f) {
  unsigned int u = __builtin_bit_cast(unsigned int, f);
  unsigned int r = (u + 0x7fffu + ((u >> 16) & 1u)) >> 16;
  return (unsigned short)r;
}

__device__ __forceinline__ float sigm(float x) { return 1.0f / (1.0f + expf(-x)); }

// LDS swizzle for weight tile wt[64][512] bf16 (row stride 1024B).
__device__ __forceinline__ int swz(int r, int k) {
  return (((r << 10) + (k << 1)) ^ ((r & 7) << 4)) >> 1;  // ushort index
}

// ---- LLC-coherent h-buffer access: relaxed agent-scope atomics lower to
// sc0/sc1 loads/stores that bypass the non-coherent per-XCD L2. No fences.
__device__ __forceinline__ short8 ld_h16(const unsigned short* p) {
  unsigned long long lo = __hip_atomic_load((const unsigned long long*)p,
                                            __ATOMIC_RELAXED, __HIP_MEMORY_SCOPE_AGENT);
  unsigned long long hi = __hip_atomic_load((const unsigned long long*)(p + 4),
                                            __ATOMIC_RELAXED, __HIP_MEMORY_SCOPE_AGENT);
  union { unsigned long long q[2]; short8 v; } u;
  u.q[0] = lo; u.q[1] = hi;
  return u.v;
}
__device__ __forceinline__ void st_h(unsigned short* p, unsigned short v) {
  __hip_atomic_store(p, v, __ATOMIC_RELAXED, __HIP_MEMORY_SCOPE_AGENT);
}

// Barrier: cumulative arrival counter at the LLC. s_waitcnt guarantees our
// coherent h stores have reached the LLC before the arrival is visible.
__device__ __forceinline__ void team_arrive(unsigned int* bar) {
  asm volatile("s_waitcnt vmcnt(0) lgkmcnt(0)" ::: "memory");
  if (threadIdx.x == 0)
    __hip_atomic_fetch_add(bar, 1u, __ATOMIC_RELAXED, __HIP_MEMORY_SCOPE_AGENT);
}
__device__ __forceinline__ void team_wait(unsigned int* bar, unsigned int target) {
  if (threadIdx.x == 0) {
    while (__hip_atomic_load(bar, __ATOMIC_RELAXED, __HIP_MEMORY_SCOPE_AGENT) < target)
      __builtin_amdgcn_s_sleep(1);
  }
  asm volatile("" ::: "memory");
}

// ---------------- conv encoder (fp32) ----------------

__global__ void conv1_kernel(const float* __restrict__ imu, const float* __restrict__ k1,
                             const float* __restrict__ g1, const float* __restrict__ b1,
                             const float* __restrict__ m1, const float* __restrict__ v1,
                             float* __restrict__ y1) {
  int idx = blockIdx.x * 256 + threadIdx.x;   // [B][T][64]
  int c = idx & 63;
  int t = (idx >> 6) & (T_SEQ - 1);
  int b = idx >> 16;
  float acc = 0.f;
#pragma unroll
  for (int dt = 0; dt < 3; ++dt) {
    int tt = t + dt - 1;
    if (tt >= 0 && tt < T_SEQ) {
      const float* ip = imu + ((size_t)b * T_SEQ + tt) * 6;
#pragma unroll
      for (int ci = 0; ci < 6; ++ci)
        acc += ip[ci] * k1[(dt * 6 + ci) * 64 + c];
    }
  }
  float sc = g1[c] * rsqrtf(v1[c] + 1e-3f);
  float y = (acc - m1[c]) * sc + b1[c];
  y1[idx] = y > 0.f ? y : 0.1f * y;
}

__global__ __launch_bounds__(128) void conv2_kernel(
    const float* __restrict__ y1, const float* __restrict__ k2,
    const float* __restrict__ g2, const float* __restrict__ b2,
    const float* __restrict__ m2, const float* __restrict__ v2,
    float* __restrict__ y2) {
  __shared__ float yt[18 * 64];
  const int b = blockIdx.x >> 6;
  const int t0 = (blockIdx.x & 63) << 4;
  for (int i = threadIdx.x; i < 18 * 64; i += 128) {
    int r = i >> 6, ci = i & 63;
    int tt = t0 - 1 + r;
    yt[i] = (tt >= 0 && tt < T_SEQ) ? y1[((size_t)b * T_SEQ + tt) * 64 + ci] : 0.f;
  }
  __syncthreads();
  const int c = threadIdx.x;
  float acc[16];
#pragma unroll
  for (int u = 0; u < 16; ++u) acc[u] = 0.f;
  for (int ci = 0; ci < 64; ++ci) {
    float w0 = k2[(0 * 64 + ci) * 128 + c];
    float w1 = k2[(1 * 64 + ci) * 128 + c];
    float w2 = k2[(2 * 64 + ci) * 128 + c];
    float rv[18];
#pragma unroll
    for (int r = 0; r < 18; ++r) rv[r] = yt[r * 64 + ci];
#pragma unroll
    for (int u = 0; u < 16; ++u)
      acc[u] += rv[u] * w0 + rv[u + 1] * w1 + rv[u + 2] * w2;
  }
  float sc = g2[c] * rsqrtf(v2[c] + 1e-3f);
  float sh = b2[c] - m2[c] * sc;
#pragma unroll
  for (int u = 0; u < 16; ++u) {
    float y = acc[u] * sc + sh;
    y2[((size_t)b * T_SEQ + (t0 + u)) * 128 + c] = y > 0.f ? y : 0.1f * y;
  }
}

__global__ __launch_bounds__(128) void conv3_kernel(
    const float* __restrict__ y2, const float* __restrict__ k3,
    const float* __restrict__ g3, const float* __restrict__ b3,
    const float* __restrict__ m3, const float* __restrict__ v3,
    unsigned short* __restrict__ x) {  // x: [T][B][256] bf16
  __shared__ float yt[18 * 128];
  const int b = blockIdx.x >> 6;
  const int t0 = (blockIdx.x & 63) << 4;
  for (int i = threadIdx.x; i < 18 * 128; i += 128) {
    int r = i >> 7, ci = i & 127;
    int tt = t0 - 1 + r;
    yt[i] = (tt >= 0 && tt < T_SEQ) ? y2[((size_t)b * T_SEQ + tt) * 128 + ci] : 0.f;
  }
  __syncthreads();
  const int c0 = threadIdx.x;  // channels c0 and c0+128
  float acc0[16], acc1[16];
#pragma unroll
  for (int u = 0; u < 16; ++u) { acc0[u] = 0.f; acc1[u] = 0.f; }
  for (int ci = 0; ci < 128; ++ci) {
    float w00 = k3[(0 * 128 + ci) * 256 + c0];
    float w01 = k3[(1 * 128 + ci) * 256 + c0];
    float w02 = k3[(2 * 128 + ci) * 256 + c0];
    float w10 = k3[(0 * 128 + ci) * 256 + c0 + 128];
    float w11 = k3[(1 * 128 + ci) * 256 + c0 + 128];
    float w12 = k3[(2 * 128 + ci) * 256 + c0 + 128];
    float rv[18];
#pragma unroll
    for (int r = 0; r < 18; ++r) rv[r] = yt[r * 128 + ci];
#pragma unroll
    for (int u = 0; u < 16; ++u) {
      acc0[u] += rv[u] * w00 + rv[u + 1] * w01 + rv[u + 2] * w02;
      acc1[u] += rv[u] * w10 + rv[u + 1] * w11 + rv[u + 2] * w12;
    }
  }
  float sca = g3[c0] * rsqrtf(v3[c0] + 1e-3f);
  float sha = b3[c0] - m3[c0] * sca;
  float scb = g3[c0 + 128] * rsqrtf(v3[c0 + 128] + 1e-3f);
  float shb = b3[c0 + 128] - m3[c0 + 128] * scb;
#pragma unroll
  for (int u = 0; u < 16; ++u) {
    float ya = acc0[u] * sca + sha;
    float yb = acc1[u] * scb + shb;
    ya = ya > 0.f ? ya : 0.1f * ya;
    yb = yb > 0.f ? yb : 0.1f * yb;
    size_t base = ((size_t)(t0 + u) * NB + b) * HID;
    x[base + c0] = f2bf(ya);
    x[base + c0 + 128] = f2bf(yb);
  }
}

// ---------------- persistent pipelined LSTM ----------------
// Grid: 256 blocks x 64 threads. Team = 32 blocks (16 L1 + 16 L2), owns 16
// batch rows. Block owns 16 h-columns (all 4 gates) of its layer. Phase ph:
// L1 computes t=ph, L2 computes t=ph-1; one LLC barrier per phase. L1 hides
// the barrier wait by precomputing x@W for t=ph+1 between arrive and wait.

__global__ __launch_bounds__(64) void lstm_kernel(
    const unsigned short* __restrict__ x,   // [T][NB][256] bf16
    const float* __restrict__ W1, const float* __restrict__ U1, const float* __restrict__ bl1,
    const float* __restrict__ W2, const float* __restrict__ U2, const float* __restrict__ bl2,
    unsigned short* __restrict__ hbufs,     // [8 teams][2 layers][2 bufs][16][256] bf16, zeroed
    unsigned int* __restrict__ bars,        // [8 teams][64] u32, zeroed
    float* __restrict__ out) {              // [128][256]
  __shared__ unsigned short wt[64 * 512];   // 64 KiB weight slice, swizzled

  const int team = blockIdx.x >> 5;
  const int bid = blockIdx.x & 31;
  const bool is_l2 = bid >= 16;
  const int j0 = (bid & 15) << 4;
  const int lane = threadIdx.x;
  const int b0 = team << 4;

  const float* Wx = is_l2 ? W2 : W1;
  const float* Wh = is_l2 ? U2 : U1;
  const float* bl = is_l2 ? bl2 : bl1;

  {  // stage weight slice into LDS
    const int r = lane;
    const int col = ((r >> 4) << 8) + j0 + (r & 15);  // g*256 + j0 + jj
    for (int k0 = 0; k0 < 256; k0 += 8) {
      short8 sx, sh;
#pragma unroll
      for (int u = 0; u < 8; ++u) {
        sx[u] = (short)f2bf(Wx[(size_t)(k0 + u) * 1024 + col]);
        sh[u] = (short)f2bf(Wh[(size_t)(k0 + u) * 1024 + col]);
      }
      *(short8*)&wt[swz(r, k0)] = sx;
      *(short8*)&wt[swz(r, 256 + k0)] = sh;
    }
  }

  const int lo4 = lane & 15;          // A-row / B-col / D-col
  const int klo = (lane >> 4) << 3;   // k-base within 32-wide K step

  float bias[4];
#pragma unroll
  for (int g = 0; g < 4; ++g) bias[g] = bl[(g << 8) + j0 + lo4];

  unsigned short* h1buf = hbufs + (size_t)team * 16384;  // [2][16][256]
  unsigned short* h2buf = h1buf + 8192;
  unsigned int* bar = bars + team * 64;

  float cst[4] = {0.f, 0.f, 0.f, 0.f};
  float oacc[4] = {0.f, 0.f, 0.f, 0.f};
  f32x4 acc[4];

  if (!is_l2) {  // prologue: bias + x@W for t=0
#pragma unroll
    for (int g = 0; g < 4; ++g) acc[g] = (f32x4){bias[g], bias[g], bias[g], bias[g]};
    const unsigned short* xs = x + (size_t)(b0 + lo4) * HID;
#pragma unroll
    for (int kk = 0; kk < 8; ++kk) {
      short8 a = *(const short8*)(xs + kk * 32 + klo);
#pragma unroll
      for (int g = 0; g < 4; ++g)
        acc[g] = __builtin_amdgcn_mfma_f32_16x16x32_bf16(
            a, *(const short8*)&wt[swz((g << 4) + lo4, (kk << 5) + klo)], acc[g], 0, 0, 0);
    }
  }

  for (int ph = 0; ph <= T_SEQ; ++ph) {
    if (!is_l2) {
      if (ph < T_SEQ) {
        // finish z for t=ph: add h1[ph-1] @ U
        const unsigned short* hs = h1buf + ((ph + 1) & 1) * 4096 + lo4 * 256;
#pragma unroll
        for (int kk = 0; kk < 8; ++kk) {
          short8 a = ld_h16(hs + kk * 32 + klo);
#pragma unroll
          for (int g = 0; g < 4; ++g)
            acc[g] = __builtin_amdgcn_mfma_f32_16x16x32_bf16(
                a, *(const short8*)&wt[swz((g << 4) + lo4, 256 + (kk << 5) + klo)], acc[g], 0, 0, 0);
        }
        unsigned short* dst = h1buf + (ph & 1) * 4096;
#pragma unroll
        for (int q = 0; q < 4; ++q) {
          float iv = acc[0][q], fv = acc[1][q], gv = acc[2][q], ov = acc[3][q];
          float cn = sigm(fv) * cst[q] + sigm(iv) * tanhf(gv);
          float hn = sigm(ov) * tanhf(cn);
          cst[q] = cn;
          int row = ((lane >> 4) << 2) + q;
          st_h(&dst[row * 256 + j0 + lo4], f2bf(hn));
        }
        team_arrive(bar);
        if (ph + 1 < T_SEQ) {  // hide the wait: bias + x@W for t=ph+1
#pragma unroll
          for (int g = 0; g < 4; ++g) acc[g] = (f32x4){bias[g], bias[g], bias[g], bias[g]};
          const unsigned short* xs = x + ((size_t)(ph + 1) * NB + b0 + lo4) * HID;
#pragma unroll
          for (int kk = 0; kk < 8; ++kk) {
            short8 a = *(const short8*)(xs + kk * 32 + klo);
#pragma unroll
            for (int g = 0; g < 4; ++g)
              acc[g] = __builtin_amdgcn_mfma_f32_16x16x32_bf16(
                  a, *(const short8*)&wt[swz((g << 4) + lo4, (kk << 5) + klo)], acc[g], 0, 0, 0);
          }
          team_wait(bar, (unsigned)(ph + 1) * TEAM_BLK);
        }
        // at ph == T_SEQ-1: arrived; nothing left to read -> no wait, fall out
      }
    } else {
      const int t = ph - 1;
      if (t >= 0) {
        const unsigned short* s0 = h1buf + (t & 1) * 4096 + lo4 * 256;        // h1[t]
        const unsigned short* s1 = h2buf + ((t + 1) & 1) * 4096 + lo4 * 256;  // h2[t-1]
#pragma unroll
        for (int g = 0; g < 4; ++g) acc[g] = (f32x4){bias[g], bias[g], bias[g], bias[g]};
#pragma unroll
        for (int kk = 0; kk < 8; ++kk) {
          short8 a = ld_h16(s0 + kk * 32 + klo);
#pragma unroll
          for (int g = 0; g < 4; ++g)
            acc[g] = __builtin_amdgcn_mfma_f32_16x16x32_bf16(
                a, *(const short8*)&wt[swz((g << 4) + lo4, (kk << 5) + klo)], acc[g], 0, 0, 0);
        }
#pragma unroll
        for (int kk = 0; kk < 8; ++kk) {
          short8 a = ld_h16(s1 + kk * 32 + klo);
#pragma unroll
          for (int g = 0; g < 4; ++g)
            acc[g] = __builtin_amdgcn_mfma_f32_16x16x32_bf16(
                a, *(const short8*)&wt[swz((g << 4) + lo4, 256 + (kk << 5) + klo)], acc[g], 0, 0, 0);
        }
        unsigned short* dst = h2buf + (t & 1) * 4096;
#pragma unroll
        for (int q = 0; q < 4; ++q) {
          float iv = acc[0][q], fv = acc[1][q], gv = acc[2][q], ov = acc[3][q];
          float cn = sigm(fv) * cst[q] + sigm(iv) * tanhf(gv);
          float hn = sigm(ov) * tanhf(cn);
          cst[q] = cn;
          int row = ((lane >> 4) << 2) + q;
          st_h(&dst[row * 256 + j0 + lo4], f2bf(hn));
          oacc[q] += hn;
        }
      }
      if (ph < T_SEQ) {
        team_arrive(bar);
        team_wait(bar, (unsigned)(ph + 1) * TEAM_BLK);
      }
    }
  }

  if (is_l2) {
#pragma unroll
    for (int q = 0; q < 4; ++q) {
      int row = ((lane >> 4) << 2) + q;
      out[(size_t)(b0 + row) * HID + j0 + lo4] = oacc[q] * (1.0f / T_SEQ);
    }
  }
}

// ---------------- host ----------------

extern "C" void kernel_launch(void* const* d_in, const int* in_sizes, int n_in,
                              void* d_out, int out_size, void* d_ws, size_t ws_size,
                              hipStream_t stream) {
  const float* imu = (const float*)d_in[0];
  const float* k1 = (const float*)d_in[1];
  const float* g1 = (const float*)d_in[2];
  const float* b1 = (const float*)d_in[3];
  const float* m1 = (const float*)d_in[4];
  const float* v1 = (const float*)d_in[5];
  const float* k2 = (const float*)d_in[6];
  const float* g2 = (const float*)d_in[7];
  const float* b2 = (const float*)d_in[8];
  const float* m2 = (const float*)d_in[9];
  const float* v2 = (const float*)d_in[10];
  const float* k3 = (const float*)d_in[11];
  const float* g3 = (const float*)d_in[12];
  const float* b3 = (const float*)d_in[13];
  const float* m3 = (const float*)d_in[14];
  const float* v3 = (const float*)d_in[15];
  const float* W1 = (const float*)d_in[16];
  const float* U1 = (const float*)d_in[17];
  const float* bl1 = (const float*)d_in[18];
  const float* W2 = (const float*)d_in[19];
  const float* U2 = (const float*)d_in[20];
  const float* bl2 = (const float*)d_in[21];

  char* ws = (char*)d_ws;
  // [0,64Mi) y2 fp32 [B][T][128]; [64Mi,96Mi) y1 fp32 [B][T][64];
  // [64Mi,128Mi) x bf16 [T][B][256] (overlaps y1; y1 dead after conv2);
  // [128Mi,+256Ki) h buffers; then barrier words.
  float* y2 = (float*)ws;
  float* y1 = (float*)(ws + (64u << 20));
  unsigned short* xq = (unsigned short*)(ws + (64u << 20));
  unsigned short* hbufs = (unsigned short*)(ws + (128u << 20));
  unsigned int* bars = (unsigned int*)(ws + (128u << 20) + (256u << 10));

  hipMemsetAsync(ws + (128u << 20), 0, (256u << 10) + 2048, stream);

  conv1_kernel<<<32768, 256, 0, stream>>>(imu, k1, g1, b1, m1, v1, y1);
  conv2_kernel<<<8192, 128, 0, stream>>>(y1, k2, g2, b2, m2, v2, y2);
  conv3_kernel<<<8192, 128, 0, stream>>>(y2, k3, g3, b3, m3, v3, xq);
  lstm_kernel<<<256, 64, 0, stream>>>(xq, W1, U1, bl1, W2, U2, bl2, hbufs, bars,
                                      (float*)d_out);
}

// Round 3
// 5282.353 us; speedup vs baseline: 5.1579x; 1.4095x over previous
//
#include <hip/hip_runtime.h>
#include <hip/hip_bf16.h>

#define T_SEQ 1024
#define NB 128
#define HID 256
#define TEAM_BLK 32

typedef __attribute__((ext_vector_type(8))) short short8;
typedef __attribute__((ext_vector_type(4))) float f32x4;

__device__ __forceinline__ unsigned short f2bf(float f) {
  unsigned int u = __builtin_bit_cast(unsigned int, f);
  unsigned int r = (u + 0x7fffu + ((u >> 16) & 1u)) >> 16;
  return (unsigned short)r;
}

__device__ __forceinline__ float sigm(float x) { return 1.0f / (1.0f + expf(-x)); }

// LDS swizzle for weight tile wt[64][512] bf16 (row stride 1024B).
__device__ __forceinline__ int swz(int r, int k) {
  return (((r << 10) + (k << 1)) ^ ((r & 7) << 4)) >> 1;  // ushort index
}

// ---- LLC-coherent h-buffer access (sc0/sc1, bypass non-coherent L2). ----
__device__ __forceinline__ short8 ld_h16(const unsigned short* p) {
  unsigned long long lo = __hip_atomic_load((const unsigned long long*)p,
                                            __ATOMIC_RELAXED, __HIP_MEMORY_SCOPE_AGENT);
  unsigned long long hi = __hip_atomic_load((const unsigned long long*)(p + 4),
                                            __ATOMIC_RELAXED, __HIP_MEMORY_SCOPE_AGENT);
  union { unsigned long long q[2]; short8 v; } u;
  u.q[0] = lo; u.q[1] = hi;
  return u.v;
}
__device__ __forceinline__ void st_h(unsigned short* p, unsigned short v) {
  __hip_atomic_store(p, v, __ATOMIC_RELAXED, __HIP_MEMORY_SCOPE_AGENT);
}

// ---- flag-array barrier: NO atomic RMW. Block bid publishes phase count to
// flags[bid] (plain coherent store after vmcnt drain); waiters read all 32
// flags with one coalesced 128B request (lane i reads flags[i&31]) + __all.
__device__ __forceinline__ void team_arrive(unsigned int* flags, int bid, unsigned int val) {
  asm volatile("s_waitcnt vmcnt(0) lgkmcnt(0)" ::: "memory");
  if (threadIdx.x == 0)
    __hip_atomic_store(flags + bid, val, __ATOMIC_RELAXED, __HIP_MEMORY_SCOPE_AGENT);
}
__device__ __forceinline__ void team_wait(const unsigned int* flags, unsigned int val) {
  const unsigned int* p = flags + (threadIdx.x & 31);
  for (;;) {
    unsigned int v = __hip_atomic_load(p, __ATOMIC_RELAXED, __HIP_MEMORY_SCOPE_AGENT);
    if (__all(v >= val)) break;
    __builtin_amdgcn_s_sleep(1);
  }
  asm volatile("" ::: "memory");
}

// ---------------- conv encoder (fp32) ----------------

__global__ void conv1_kernel(const float* __restrict__ imu, const float* __restrict__ k1,
                             const float* __restrict__ g1, const float* __restrict__ b1,
                             const float* __restrict__ m1, const float* __restrict__ v1,
                             float* __restrict__ y1) {
  int idx = blockIdx.x * 256 + threadIdx.x;   // [B][T][64]
  int c = idx & 63;
  int t = (idx >> 6) & (T_SEQ - 1);
  int b = idx >> 16;
  float acc = 0.f;
#pragma unroll
  for (int dt = 0; dt < 3; ++dt) {
    int tt = t + dt - 1;
    if (tt >= 0 && tt < T_SEQ) {
      const float* ip = imu + ((size_t)b * T_SEQ + tt) * 6;
#pragma unroll
      for (int ci = 0; ci < 6; ++ci)
        acc += ip[ci] * k1[(dt * 6 + ci) * 64 + c];
    }
  }
  float sc = g1[c] * rsqrtf(v1[c] + 1e-3f);
  float y = (acc - m1[c]) * sc + b1[c];
  y1[idx] = y > 0.f ? y : 0.1f * y;
}

__global__ __launch_bounds__(128) void conv2_kernel(
    const float* __restrict__ y1, const float* __restrict__ k2,
    const float* __restrict__ g2, const float* __restrict__ b2,
    const float* __restrict__ m2, const float* __restrict__ v2,
    float* __restrict__ y2) {
  __shared__ float yt[18 * 64];
  const int b = blockIdx.x >> 6;
  const int t0 = (blockIdx.x & 63) << 4;
  for (int i = threadIdx.x; i < 18 * 64; i += 128) {
    int r = i >> 6, ci = i & 63;
    int tt = t0 - 1 + r;
    yt[i] = (tt >= 0 && tt < T_SEQ) ? y1[((size_t)b * T_SEQ + tt) * 64 + ci] : 0.f;
  }
  __syncthreads();
  const int c = threadIdx.x;
  float acc[16];
#pragma unroll
  for (int u = 0; u < 16; ++u) acc[u] = 0.f;
  for (int ci = 0; ci < 64; ++ci) {
    float w0 = k2[(0 * 64 + ci) * 128 + c];
    float w1 = k2[(1 * 64 + ci) * 128 + c];
    float w2 = k2[(2 * 64 + ci) * 128 + c];
    float rv[18];
#pragma unroll
    for (int r = 0; r < 18; ++r) rv[r] = yt[r * 64 + ci];
#pragma unroll
    for (int u = 0; u < 16; ++u)
      acc[u] += rv[u] * w0 + rv[u + 1] * w1 + rv[u + 2] * w2;
  }
  float sc = g2[c] * rsqrtf(v2[c] + 1e-3f);
  float sh = b2[c] - m2[c] * sc;
#pragma unroll
  for (int u = 0; u < 16; ++u) {
    float y = acc[u] * sc + sh;
    y2[((size_t)b * T_SEQ + (t0 + u)) * 128 + c] = y > 0.f ? y : 0.1f * y;
  }
}

__global__ __launch_bounds__(128) void conv3_kernel(
    const float* __restrict__ y2, const float* __restrict__ k3,
    const float* __restrict__ g3, const float* __restrict__ b3,
    const float* __restrict__ m3, const float* __restrict__ v3,
    unsigned short* __restrict__ x) {  // x: [T][B][256] bf16
  __shared__ float yt[18 * 128];
  const int b = blockIdx.x >> 6;
  const int t0 = (blockIdx.x & 63) << 4;
  for (int i = threadIdx.x; i < 18 * 128; i += 128) {
    int r = i >> 7, ci = i & 127;
    int tt = t0 - 1 + r;
    yt[i] = (tt >= 0 && tt < T_SEQ) ? y2[((size_t)b * T_SEQ + tt) * 128 + ci] : 0.f;
  }
  __syncthreads();
  const int c0 = threadIdx.x;  // channels c0 and c0+128
  float acc0[16], acc1[16];
#pragma unroll
  for (int u = 0; u < 16; ++u) { acc0[u] = 0.f; acc1[u] = 0.f; }
  for (int ci = 0; ci < 128; ++ci) {
    float w00 = k3[(0 * 128 + ci) * 256 + c0];
    float w01 = k3[(1 * 128 + ci) * 256 + c0];
    float w02 = k3[(2 * 128 + ci) * 256 + c0];
    float w10 = k3[(0 * 128 + ci) * 256 + c0 + 128];
    float w11 = k3[(1 * 128 + ci) * 256 + c0 + 128];
    float w12 = k3[(2 * 128 + ci) * 256 + c0 + 128];
    float rv[18];
#pragma unroll
    for (int r = 0; r < 18; ++r) rv[r] = yt[r * 128 + ci];
#pragma unroll
    for (int u = 0; u < 16; ++u) {
      acc0[u] += rv[u] * w00 + rv[u + 1] * w01 + rv[u + 2] * w02;
      acc1[u] += rv[u] * w10 + rv[u + 1] * w11 + rv[u + 2] * w12;
    }
  }
  float sca = g3[c0] * rsqrtf(v3[c0] + 1e-3f);
  float sha = b3[c0] - m3[c0] * sca;
  float scb = g3[c0 + 128] * rsqrtf(v3[c0 + 128] + 1e-3f);
  float shb = b3[c0 + 128] - m3[c0 + 128] * scb;
#pragma unroll
  for (int u = 0; u < 16; ++u) {
    float ya = acc0[u] * sca + sha;
    float yb = acc1[u] * scb + shb;
    ya = ya > 0.f ? ya : 0.1f * ya;
    yb = yb > 0.f ? yb : 0.1f * yb;
    size_t base = ((size_t)(t0 + u) * NB + b) * HID;
    x[base + c0] = f2bf(ya);
    x[base + c0 + 128] = f2bf(yb);
  }
}

// ---------------- persistent pipelined LSTM ----------------
// Grid: 256 blocks x 64 threads. Team = 32 blocks (16 L1 + 16 L2), owns 16
// batch rows. Block owns 16 h-columns (all 4 gates) of its layer. Phase ph:
// L1 computes t=ph, L2 computes t=ph-1; one flag-array barrier per phase.
// L1 hides the wait by precomputing x@W for t=ph+1 between arrive and wait.

__global__ __launch_bounds__(64) void lstm_kernel(
    const unsigned short* __restrict__ x,   // [T][NB][256] bf16
    const float* __restrict__ W1, const float* __restrict__ U1, const float* __restrict__ bl1,
    const float* __restrict__ W2, const float* __restrict__ U2, const float* __restrict__ bl2,
    unsigned short* __restrict__ hbufs,     // [8 teams][2 layers][2 bufs][16][256] bf16, zeroed
    unsigned int* __restrict__ bars,        // [8 teams][64] u32, zeroed
    float* __restrict__ out) {              // [128][256]
  __shared__ unsigned short wt[64 * 512];   // 64 KiB weight slice, swizzled

  const int team = blockIdx.x >> 5;
  const int bid = blockIdx.x & 31;
  const bool is_l2 = bid >= 16;
  const int j0 = (bid & 15) << 4;
  const int lane = threadIdx.x;
  const int b0 = team << 4;

  const float* Wx = is_l2 ? W2 : W1;
  const float* Wh = is_l2 ? U2 : U1;
  const float* bl = is_l2 ? bl2 : bl1;

  {  // stage weight slice into LDS
    const int r = lane;
    const int col = ((r >> 4) << 8) + j0 + (r & 15);  // g*256 + j0 + jj
    for (int k0 = 0; k0 < 256; k0 += 8) {
      short8 sx, sh;
#pragma unroll
      for (int u = 0; u < 8; ++u) {
        sx[u] = (short)f2bf(Wx[(size_t)(k0 + u) * 1024 + col]);
        sh[u] = (short)f2bf(Wh[(size_t)(k0 + u) * 1024 + col]);
      }
      *(short8*)&wt[swz(r, k0)] = sx;
      *(short8*)&wt[swz(r, 256 + k0)] = sh;
    }
  }

  const int lo4 = lane & 15;          // A-row / B-col / D-col
  const int klo = (lane >> 4) << 3;   // k-base within 32-wide K step

  float bias[4];
#pragma unroll
  for (int g = 0; g < 4; ++g) bias[g] = bl[(g << 8) + j0 + lo4];

  unsigned short* h1buf = hbufs + (size_t)team * 16384;  // [2][16][256]
  unsigned short* h2buf = h1buf + 8192;
  unsigned int* flags = bars + team * 64;

  float cst[4] = {0.f, 0.f, 0.f, 0.f};
  float oacc[4] = {0.f, 0.f, 0.f, 0.f};
  f32x4 acc[4];

  if (!is_l2) {  // prologue: bias + x@W for t=0
#pragma unroll
    for (int g = 0; g < 4; ++g) acc[g] = (f32x4){bias[g], bias[g], bias[g], bias[g]};
    const unsigned short* xs = x + (size_t)(b0 + lo4) * HID;
#pragma unroll
    for (int kk = 0; kk < 8; ++kk) {
      short8 a = *(const short8*)(xs + kk * 32 + klo);
#pragma unroll
      for (int g = 0; g < 4; ++g)
        acc[g] = __builtin_amdgcn_mfma_f32_16x16x32_bf16(
            a, *(const short8*)&wt[swz((g << 4) + lo4, (kk << 5) + klo)], acc[g], 0, 0, 0);
    }
  }

  for (int ph = 0; ph <= T_SEQ; ++ph) {
    if (!is_l2) {
      if (ph < T_SEQ) {
        // finish z for t=ph: add h1[ph-1] @ U  (load all a-frags up front)
        const unsigned short* hs = h1buf + ((ph + 1) & 1) * 4096 + lo4 * 256;
        short8 av[8];
#pragma unroll
        for (int kk = 0; kk < 8; ++kk) av[kk] = ld_h16(hs + kk * 32 + klo);
#pragma unroll
        for (int kk = 0; kk < 8; ++kk)
#pragma unroll
          for (int g = 0; g < 4; ++g)
            acc[g] = __builtin_amdgcn_mfma_f32_16x16x32_bf16(
                av[kk], *(const short8*)&wt[swz((g << 4) + lo4, 256 + (kk << 5) + klo)],
                acc[g], 0, 0, 0);
        unsigned short* dst = h1buf + (ph & 1) * 4096;
#pragma unroll
        for (int q = 0; q < 4; ++q) {
          float iv = acc[0][q], fv = acc[1][q], gv = acc[2][q], ov = acc[3][q];
          float cn = sigm(fv) * cst[q] + sigm(iv) * tanhf(gv);
          float hn = sigm(ov) * tanhf(cn);
          cst[q] = cn;
          int row = ((lane >> 4) << 2) + q;
          st_h(&dst[row * 256 + j0 + lo4], f2bf(hn));
        }
        team_arrive(flags, bid, (unsigned)(ph + 1));
        if (ph + 1 < T_SEQ) {  // hide the wait: bias + x@W for t=ph+1
#pragma unroll
          for (int g = 0; g < 4; ++g) acc[g] = (f32x4){bias[g], bias[g], bias[g], bias[g]};
          const unsigned short* xs = x + ((size_t)(ph + 1) * NB + b0 + lo4) * HID;
#pragma unroll
          for (int kk = 0; kk < 8; ++kk) {
            short8 a = *(const short8*)(xs + kk * 32 + klo);
#pragma unroll
            for (int g = 0; g < 4; ++g)
              acc[g] = __builtin_amdgcn_mfma_f32_16x16x32_bf16(
                  a, *(const short8*)&wt[swz((g << 4) + lo4, (kk << 5) + klo)], acc[g], 0, 0, 0);
          }
          team_wait(flags, (unsigned)(ph + 1));
        }
      }
    } else {
      const int t = ph - 1;
      if (t >= 0) {
        const unsigned short* s0 = h1buf + (t & 1) * 4096 + lo4 * 256;        // h1[t]
        const unsigned short* s1 = h2buf + ((t + 1) & 1) * 4096 + lo4 * 256;  // h2[t-1]
        short8 a0[8], a1[8];
#pragma unroll
        for (int kk = 0; kk < 8; ++kk) a0[kk] = ld_h16(s0 + kk * 32 + klo);
#pragma unroll
        for (int kk = 0; kk < 8; ++kk) a1[kk] = ld_h16(s1 + kk * 32 + klo);
#pragma unroll
        for (int g = 0; g < 4; ++g) acc[g] = (f32x4){bias[g], bias[g], bias[g], bias[g]};
#pragma unroll
        for (int kk = 0; kk < 8; ++kk)
#pragma unroll
          for (int g = 0; g < 4; ++g)
            acc[g] = __builtin_amdgcn_mfma_f32_16x16x32_bf16(
                a0[kk], *(const short8*)&wt[swz((g << 4) + lo4, (kk << 5) + klo)],
                acc[g], 0, 0, 0);
#pragma unroll
        for (int kk = 0; kk < 8; ++kk)
#pragma unroll
          for (int g = 0; g < 4; ++g)
            acc[g] = __builtin_amdgcn_mfma_f32_16x16x32_bf16(
                a1[kk], *(const short8*)&wt[swz((g << 4) + lo4, 256 + (kk << 5) + klo)],
                acc[g], 0, 0, 0);
        unsigned short* dst = h2buf + (t & 1) * 4096;
#pragma unroll
        for (int q = 0; q < 4; ++q) {
          float iv = acc[0][q], fv = acc[1][q], gv = acc[2][q], ov = acc[3][q];
          float cn = sigm(fv) * cst[q] + sigm(iv) * tanhf(gv);
          float hn = sigm(ov) * tanhf(cn);
          cst[q] = cn;
          int row = ((lane >> 4) << 2) + q;
          st_h(&dst[row * 256 + j0 + lo4], f2bf(hn));
          oacc[q] += hn;
        }
      }
      if (ph < T_SEQ) {
        team_arrive(flags, bid, (unsigned)(ph + 1));
        team_wait(flags, (unsigned)(ph + 1));
      }
    }
  }

  if (is_l2) {
#pragma unroll
    for (int q = 0; q < 4; ++q) {
      int row = ((lane >> 4) << 2) + q;
      out[(size_t)(b0 + row) * HID + j0 + lo4] = oacc[q] * (1.0f / T_SEQ);
    }
  }
}

// ---------------- host ----------------

extern "C" void kernel_launch(void* const* d_in, const int* in_sizes, int n_in,
                              void* d_out, int out_size, void* d_ws, size_t ws_size,
                              hipStream_t stream) {
  const float* imu = (const float*)d_in[0];
  const float* k1 = (const float*)d_in[1];
  const float* g1 = (const float*)d_in[2];
  const float* b1 = (const float*)d_in[3];
  const float* m1 = (const float*)d_in[4];
  const float* v1 = (const float*)d_in[5];
  const float* k2 = (const float*)d_in[6];
  const float* g2 = (const float*)d_in[7];
  const float* b2 = (const float*)d_in[8];
  const float* m2 = (const float*)d_in[9];
  const float* v2 = (const float*)d_in[10];
  const float* k3 = (const float*)d_in[11];
  const float* g3 = (const float*)d_in[12];
  const float* b3 = (const float*)d_in[13];
  const float* m3 = (const float*)d_in[14];
  const float* v3 = (const float*)d_in[15];
  const float* W1 = (const float*)d_in[16];
  const float* U1 = (const float*)d_in[17];
  const float* bl1 = (const float*)d_in[18];
  const float* W2 = (const float*)d_in[19];
  const float* U2 = (const float*)d_in[20];
  const float* bl2 = (const float*)d_in[21];

  char* ws = (char*)d_ws;
  // [0,64Mi) y2 fp32 [B][T][128]; [64Mi,96Mi) y1 fp32 [B][T][64];
  // [64Mi,128Mi) x bf16 [T][B][256] (overlaps y1; y1 dead after conv2);
  // [128Mi,+256Ki) h buffers; then flag words.
  float* y2 = (float*)ws;
  float* y1 = (float*)(ws + (64u << 20));
  unsigned short* xq = (unsigned short*)(ws + (64u << 20));
  unsigned short* hbufs = (unsigned short*)(ws + (128u << 20));
  unsigned int* bars = (unsigned int*)(ws + (128u << 20) + (256u << 10));

  hipMemsetAsync(ws + (128u << 20), 0, (256u << 10) + 2048, stream);

  conv1_kernel<<<32768, 256, 0, stream>>>(imu, k1, g1, b1, m1, v1, y1);
  conv2_kernel<<<8192, 128, 0, stream>>>(y1, k2, g2, b2, m2, v2, y2);
  conv3_kernel<<<8192, 128, 0, stream>>>(y2, k3, g3, b3, m3, v3, xq);
  lstm_kernel<<<256, 64, 0, stream>>>(xq, W1, U1, bl1, W2, U2, bl2, hbufs, bars,
                                      (float*)d_out);
}

// Round 6
// 5032.498 us; speedup vs baseline: 5.4140x; 1.0496x over previous
//
#include <hip/hip_runtime.h>
#include <hip/hip_bf16.h>

#define T_SEQ 1024
#define NB 128
#define HID 256
#define NEGINF_TGT (-(1 << 30))

typedef __attribute__((ext_vector_type(8))) short short8;
typedef __attribute__((ext_vector_type(4))) float f32x4;

__device__ __forceinline__ unsigned short f2bf(float f) {
  unsigned int u = __builtin_bit_cast(unsigned int, f);
  unsigned int r = (u + 0x7fffu + ((u >> 16) & 1u)) >> 16;
  return (unsigned short)r;
}

__device__ __forceinline__ float sigm(float x) { return 1.0f / (1.0f + expf(-x)); }

// ---- LLC-coherent transport (R3-proven): agent-scope relaxed atomics ----
__device__ __forceinline__ short8 ld_h16(const unsigned short* p) {
  unsigned long long lo = __hip_atomic_load((const unsigned long long*)p,
                                            __ATOMIC_RELAXED, __HIP_MEMORY_SCOPE_AGENT);
  unsigned long long hi = __hip_atomic_load((const unsigned long long*)(p + 4),
                                            __ATOMIC_RELAXED, __HIP_MEMORY_SCOPE_AGENT);
  union { unsigned long long q[2]; short8 v; } u;
  u.q[0] = lo; u.q[1] = hi;
  return u.v;
}
__device__ __forceinline__ void st_h(unsigned short* p, unsigned short v) {
  __hip_atomic_store(p, v, __ATOMIC_RELAXED, __HIP_MEMORY_SCOPE_AGENT);
}

// drain all prior vmem (h stores land in LLC), then publish monotone tag
__device__ __forceinline__ void publish(int* tag, int val) {
  asm volatile("s_waitcnt vmcnt(0) lgkmcnt(0)" ::: "memory");
  if (threadIdx.x == 0)
    __hip_atomic_store(tag, val, __ATOMIC_RELAXED, __HIP_MEMORY_SCOPE_AGENT);
}

// merged dual wait: lanes 0-15 poll tags[0..15] (TAG1) vs tgtA,
// lanes 16-31 poll tags[16..31] (TAG2) vs tgtB (lanes 32-63 mirror).
__device__ __forceinline__ void wait_pair(const int* tags, int tgtA, int tgtB) {
  const int l = threadIdx.x;
  const int* p = tags + (l & 31);
  const int tgt = (l & 16) ? tgtB : tgtA;
  for (;;) {
    int v = __hip_atomic_load(p, __ATOMIC_RELAXED, __HIP_MEMORY_SCOPE_AGENT);
    if (__all(v >= tgt)) break;
  }
  asm volatile("" ::: "memory");
}

// ---------------- conv encoder (fp32) ----------------

__global__ void conv1_kernel(const float* __restrict__ imu, const float* __restrict__ k1,
                             const float* __restrict__ g1, const float* __restrict__ b1,
                             const float* __restrict__ m1, const float* __restrict__ v1,
                             float* __restrict__ y1) {
  int idx = blockIdx.x * 256 + threadIdx.x;   // [B][T][64]
  int c = idx & 63;
  int t = (idx >> 6) & (T_SEQ - 1);
  int b = idx >> 16;
  float acc = 0.f;
#pragma unroll
  for (int dt = 0; dt < 3; ++dt) {
    int tt = t + dt - 1;
    if (tt >= 0 && tt < T_SEQ) {
      const float* ip = imu + ((size_t)b * T_SEQ + tt) * 6;
#pragma unroll
      for (int ci = 0; ci < 6; ++ci)
        acc += ip[ci] * k1[(dt * 6 + ci) * 64 + c];
    }
  }
  float sc = g1[c] * rsqrtf(v1[c] + 1e-3f);
  float y = (acc - m1[c]) * sc + b1[c];
  y1[idx] = y > 0.f ? y : 0.1f * y;
}

__global__ __launch_bounds__(128) void conv2_kernel(
    const float* __restrict__ y1, const float* __restrict__ k2,
    const float* __restrict__ g2, const float* __restrict__ b2,
    const float* __restrict__ m2, const float* __restrict__ v2,
    float* __restrict__ y2) {
  __shared__ float yt[18 * 64];
  const int b = blockIdx.x >> 6;
  const int t0 = (blockIdx.x & 63) << 4;
  for (int i = threadIdx.x; i < 18 * 64; i += 128) {
    int r = i >> 6, ci = i & 63;
    int tt = t0 - 1 + r;
    yt[i] = (tt >= 0 && tt < T_SEQ) ? y1[((size_t)b * T_SEQ + tt) * 64 + ci] : 0.f;
  }
  __syncthreads();
  const int c = threadIdx.x;
  float acc[16];
#pragma unroll
  for (int u = 0; u < 16; ++u) acc[u] = 0.f;
  for (int ci = 0; ci < 64; ++ci) {
    float w0 = k2[(0 * 64 + ci) * 128 + c];
    float w1 = k2[(1 * 64 + ci) * 128 + c];
    float w2 = k2[(2 * 64 + ci) * 128 + c];
    float rv[18];
#pragma unroll
    for (int r = 0; r < 18; ++r) rv[r] = yt[r * 64 + ci];
#pragma unroll
    for (int u = 0; u < 16; ++u)
      acc[u] += rv[u] * w0 + rv[u + 1] * w1 + rv[u + 2] * w2;
  }
  float sc = g2[c] * rsqrtf(v2[c] + 1e-3f);
  float sh = b2[c] - m2[c] * sc;
#pragma unroll
  for (int u = 0; u < 16; ++u) {
    float y = acc[u] * sc + sh;
    y2[((size_t)b * T_SEQ + (t0 + u)) * 128 + c] = y > 0.f ? y : 0.1f * y;
  }
}

__global__ __launch_bounds__(128) void conv3_kernel(
    const float* __restrict__ y2, const float* __restrict__ k3,
    const float* __restrict__ g3, const float* __restrict__ b3,
    const float* __restrict__ m3, const float* __restrict__ v3,
    unsigned short* __restrict__ x) {  // x: [T][B][256] bf16
  __shared__ float yt[18 * 128];
  const int b = blockIdx.x >> 6;
  const int t0 = (blockIdx.x & 63) << 4;
  for (int i = threadIdx.x; i < 18 * 128; i += 128) {
    int r = i >> 7, ci = i & 127;
    int tt = t0 - 1 + r;
    yt[i] = (tt >= 0 && tt < T_SEQ) ? y2[((size_t)b * T_SEQ + tt) * 128 + ci] : 0.f;
  }
  __syncthreads();
  const int c0 = threadIdx.x;  // channels c0 and c0+128
  float acc0[16], acc1[16];
#pragma unroll
  for (int u = 0; u < 16; ++u) { acc0[u] = 0.f; acc1[u] = 0.f; }
  for (int ci = 0; ci < 128; ++ci) {
    float w00 = k3[(0 * 128 + ci) * 256 + c0];
    float w01 = k3[(1 * 128 + ci) * 256 + c0];
    float w02 = k3[(2 * 128 + ci) * 256 + c0];
    float w10 = k3[(0 * 128 + ci) * 256 + c0 + 128];
    float w11 = k3[(1 * 128 + ci) * 256 + c0 + 128];
    float w12 = k3[(2 * 128 + ci) * 256 + c0 + 128];
    float rv[18];
#pragma unroll
    for (int r = 0; r < 18; ++r) rv[r] = yt[r * 128 + ci];
#pragma unroll
    for (int u = 0; u < 16; ++u) {
      acc0[u] += rv[u] * w00 + rv[u + 1] * w01 + rv[u + 2] * w02;
      acc1[u] += rv[u] * w10 + rv[u + 1] * w11 + rv[u + 2] * w12;
    }
  }
  float sca = g3[c0] * rsqrtf(v3[c0] + 1e-3f);
  float sha = b3[c0] - m3[c0] * sca;
  float scb = g3[c0 + 128] * rsqrtf(v3[c0 + 128] + 1e-3f);
  float shb = b3[c0 + 128] - m3[c0 + 128] * scb;
#pragma unroll
  for (int u = 0; u < 16; ++u) {
    float ya = acc0[u] * sca + sha;
    float yb = acc1[u] * scb + shb;
    ya = ya > 0.f ? ya : 0.1f * ya;
    yb = yb > 0.f ? yb : 0.1f * yb;
    size_t base = ((size_t)(t0 + u) * NB + b) * HID;
    x[base + c0] = f2bf(ya);
    x[base + c0 + 128] = f2bf(yb);
  }
}

// ---------------- persistent pipelined LSTM ----------------
// 256 blocks x 64 threads (1 wave, ZERO LDS, weights in 256 VGPRs/lane).
// Team = 32 blocks (16 L1 + 16 L2) = blockIdx>>5, owns 16 batch rows.
// h exchange: producer-major ring H[layer][slot=ph&3][producer][16r][16c] bf16
// in LLC via agent-scope atomics. Tags: per team int[32]: [0..15]=TAG1 (L1
// block p finished phase tag-1), [16..31]=TAG2 (same for L2).
// Dep graph: L1(ph) <- L1(ph-1), L2(ph-3)[ring];  L2(ph) <- L1(ph), L2(ph-1).
// Acyclic => deadlock-free.

__global__ __launch_bounds__(64, 1) void lstm_kernel(
    const unsigned short* __restrict__ x,   // [T][NB][256] bf16
    const float* __restrict__ W1, const float* __restrict__ U1, const float* __restrict__ bl1,
    const float* __restrict__ W2, const float* __restrict__ U2, const float* __restrict__ bl2,
    unsigned short* __restrict__ hbufs,     // [8 teams][2 layers][4 slots][16p][16r][16c], zeroed
    int* __restrict__ bars,                 // [8 teams][64] int, zeroed
    float* __restrict__ out) {              // [128][256]
  const int team = blockIdx.x >> 5;
  const int bid = blockIdx.x & 31;
  const bool is_l2 = bid >= 16;
  const int pid = bid & 15;
  const int j0 = pid << 4;
  const int lane = threadIdx.x;
  const int b0 = team << 4;

  const float* Wx = is_l2 ? W2 : W1;
  const float* Wh = is_l2 ? U2 : U1;
  const float* bl = is_l2 ? bl2 : bl1;

  const int lo4 = lane & 15;          // frag col (B) / row (A) / col (D)
  const int klo = (lane >> 4) << 3;   // k-offset within 32-wide K step

  // ---- weights -> registers: wB[s][kk][g], s=0:W(x/h1-path) s=1:U ----
  short8 wB[2][8][4];
  {
    const float* Wsrc[2] = {Wx, Wh};
#pragma unroll
    for (int s = 0; s < 2; ++s)
#pragma unroll
      for (int kk = 0; kk < 8; ++kk)
#pragma unroll
        for (int g = 0; g < 4; ++g) {
          short8 v;
#pragma unroll
          for (int e = 0; e < 8; ++e)
            v[e] = (short)f2bf(Wsrc[s][(size_t)(kk * 32 + klo + e) * 1024 + (g << 8) + j0 + lo4]);
          wB[s][kk][g] = v;
        }
  }

  float bias[4];
#pragma unroll
  for (int g = 0; g < 4; ++g) bias[g] = bl[(g << 8) + j0 + lo4];

  // ring buffers: per team 2 layers x 4 slots x 4096 ushorts
  unsigned short* h1b = hbufs + (size_t)team * 32768;
  unsigned short* h2b = h1b + 16384;
  int* tags = bars + team * 64;

  // per-lane a-frag offset within a slot: frag (kk) reads 16B at
  // slotbase + kk*512 + cbase   (producer p = 2kk + (klo>>4))
  const int cbase = ((klo >> 4) << 8) + (lo4 << 4) + (klo & 8);
  const int row = ((lane >> 4) << 2);  // D-frag rows row..row+3
  const int stoff = pid * 256 + row * 16 + lo4;

  float cst[4] = {0.f, 0.f, 0.f, 0.f};
  float oacc[4] = {0.f, 0.f, 0.f, 0.f};
  f32x4 acc[4];

  if (!is_l2) {
    // ---------------- layer-1 block ----------------
    // prologue: acc = bias + x[0] @ W1
#pragma unroll
    for (int g = 0; g < 4; ++g) acc[g] = (f32x4){bias[g], bias[g], bias[g], bias[g]};
    {
      const unsigned short* xs = x + (size_t)(b0 + lo4) * HID + klo;
#pragma unroll
      for (int kk = 0; kk < 8; ++kk) {
        short8 a = *(const short8*)(xs + kk * 32);
#pragma unroll
        for (int g = 0; g < 4; ++g)
          acc[g] = __builtin_amdgcn_mfma_f32_16x16x32_bf16(a, wB[0][kk][g], acc[g], 0, 0, 0);
      }
    }

    for (int ph = 0; ph < T_SEQ; ++ph) {
      // peers' h1[ph-1] ready; ring: L2 consumed h1[ph-4] (TAG2 >= ph-3)
      wait_pair(tags, ph, ph - 3);
      {
        const unsigned short* src = h1b + ((ph + 3) & 3) * 4096 + cbase;
        short8 av[8];
#pragma unroll
        for (int kk = 0; kk < 8; ++kk) av[kk] = ld_h16(src + kk * 512);
#pragma unroll
        for (int kk = 0; kk < 8; ++kk)
#pragma unroll
          for (int g = 0; g < 4; ++g)
            acc[g] = __builtin_amdgcn_mfma_f32_16x16x32_bf16(av[kk], wB[1][kk][g], acc[g], 0, 0, 0);
      }
      unsigned short* dst = h1b + (ph & 3) * 4096 + stoff;
#pragma unroll
      for (int q = 0; q < 4; ++q) {
        float iv = acc[0][q], fv = acc[1][q], gv = acc[2][q], ov = acc[3][q];
        float cn = sigm(fv) * cst[q] + sigm(iv) * tanhf(gv);
        float hn = sigm(ov) * tanhf(cn);
        cst[q] = cn;
        st_h(dst + q * 16, f2bf(hn));
      }
      // issue next x-frag loads so they complete under the store drain
      short8 xv[8];
      if (ph + 1 < T_SEQ) {
        const unsigned short* xs = x + ((size_t)(ph + 1) * NB + b0 + lo4) * HID + klo;
#pragma unroll
        for (int kk = 0; kk < 8; ++kk) xv[kk] = *(const short8*)(xs + kk * 32);
      }
      publish(&tags[pid], ph + 1);
      if (ph + 1 < T_SEQ) {  // shadow: acc = bias + x[ph+1] @ W1
#pragma unroll
        for (int g = 0; g < 4; ++g) acc[g] = (f32x4){bias[g], bias[g], bias[g], bias[g]};
#pragma unroll
        for (int kk = 0; kk < 8; ++kk)
#pragma unroll
          for (int g = 0; g < 4; ++g)
            acc[g] = __builtin_amdgcn_mfma_f32_16x16x32_bf16(xv[kk], wB[0][kk][g], acc[g], 0, 0, 0);
      }
    }
  } else {
    // ---------------- layer-2 block ----------------
    for (int ph = 0; ph < T_SEQ; ++ph) {
      wait_pair(tags, ph + 1, NEGINF_TGT);  // h1[ph] ready (early via pipeline)
#pragma unroll
      for (int g = 0; g < 4; ++g) acc[g] = (f32x4){bias[g], bias[g], bias[g], bias[g]};
      {
        const unsigned short* s1 = h1b + (ph & 3) * 4096 + cbase;
        short8 av[8];
#pragma unroll
        for (int kk = 0; kk < 8; ++kk) av[kk] = ld_h16(s1 + kk * 512);
#pragma unroll
        for (int kk = 0; kk < 8; ++kk)
#pragma unroll
          for (int g = 0; g < 4; ++g)
            acc[g] = __builtin_amdgcn_mfma_f32_16x16x32_bf16(av[kk], wB[0][kk][g], acc[g], 0, 0, 0);
      }
      wait_pair(tags, NEGINF_TGT, ph);      // peers' h2[ph-1] ready (serial path)
      {
        const unsigned short* s2 = h2b + ((ph + 3) & 3) * 4096 + cbase;
        short8 av[8];
#pragma unroll
        for (int kk = 0; kk < 8; ++kk) av[kk] = ld_h16(s2 + kk * 512);
#pragma unroll
        for (int kk = 0; kk < 8; ++kk)
#pragma unroll
          for (int g = 0; g < 4; ++g)
            acc[g] = __builtin_amdgcn_mfma_f32_16x16x32_bf16(av[kk], wB[1][kk][g], acc[g], 0, 0, 0);
      }
      unsigned short* dst = h2b + (ph & 3) * 4096 + stoff;
#pragma unroll
      for (int q = 0; q < 4; ++q) {
        float iv = acc[0][q], fv = acc[1][q], gv = acc[2][q], ov = acc[3][q];
        float cn = sigm(fv) * cst[q] + sigm(iv) * tanhf(gv);
        float hn = sigm(ov) * tanhf(cn);
        cst[q] = cn;
        st_h(dst + q * 16, f2bf(hn));
        oacc[q] += hn;
      }
      publish(&tags[16 + pid], ph + 1);
    }
#pragma unroll
    for (int q = 0; q < 4; ++q)
      out[(size_t)(b0 + row + q) * HID + j0 + lo4] = oacc[q] * (1.0f / T_SEQ);
  }
}

// ---------------- host ----------------

extern "C" void kernel_launch(void* const* d_in, const int* in_sizes, int n_in,
                              void* d_out, int out_size, void* d_ws, size_t ws_size,
                              hipStream_t stream) {
  const float* imu = (const float*)d_in[0];
  const float* k1 = (const float*)d_in[1];
  const float* g1 = (const float*)d_in[2];
  const float* b1 = (const float*)d_in[3];
  const float* m1 = (const float*)d_in[4];
  const float* v1 = (const float*)d_in[5];
  const float* k2 = (const float*)d_in[6];
  const float* g2 = (const float*)d_in[7];
  const float* b2 = (const float*)d_in[8];
  const float* m2 = (const float*)d_in[9];
  const float* v2 = (const float*)d_in[10];
  const float* k3 = (const float*)d_in[11];
  const float* g3 = (const float*)d_in[12];
  const float* b3 = (const float*)d_in[13];
  const float* m3 = (const float*)d_in[14];
  const float* v3 = (const float*)d_in[15];
  const float* W1 = (const float*)d_in[16];
  const float* U1 = (const float*)d_in[17];
  const float* bl1 = (const float*)d_in[18];
  const float* W2 = (const float*)d_in[19];
  const float* U2 = (const float*)d_in[20];
  const float* bl2 = (const float*)d_in[21];

  char* ws = (char*)d_ws;
  // [0,64Mi) y2 fp32; [64Mi,96Mi) y1 fp32; [64Mi,128Mi) x bf16 (y1 dead after conv2);
  // [128Mi..) h rings (512Ki) + tags (2Ki).
  float* y2 = (float*)ws;
  float* y1 = (float*)(ws + (64u << 20));
  unsigned short* xq = (unsigned short*)(ws + (64u << 20));
  unsigned short* hbufs = (unsigned short*)(ws + (128u << 20));
  int* bars = (int*)(ws + (128u << 20) + (512u << 10));

  hipMemsetAsync(ws + (128u << 20), 0, (512u << 10) + 2048, stream);

  conv1_kernel<<<32768, 256, 0, stream>>>(imu, k1, g1, b1, m1, v1, y1);
  conv2_kernel<<<8192, 128, 0, stream>>>(y1, k2, g2, b2, m2, v2, y2);
  conv3_kernel<<<8192, 128, 0, stream>>>(y2, k3, g3, b3, m3, v3, xq);
  lstm_kernel<<<256, 64, 0, stream>>>(xq, W1, U1, bl1, W2, U2, bl2, hbufs, bars,
                                      (float*)d_out);
}